// Round 1
// baseline (304.318 us; speedup 1.0000x reference)
//
#include <hip/hip_runtime.h>
#include <stdint.h>

#define XWORDS (65536 * 28)   // one packed 28-bit row per uint32

__device__ __forceinline__ void FA(uint32_t a, uint32_t b, uint32_t c,
                                   uint32_t& s, uint32_t& cy) {
  uint32_t ab = a ^ b;
  s = ab ^ c;
  cy = (a & b) | (ab & c);
}

// Pass 1: bit-pack sign(x) rows (1 thread = 1 image row of 28 floats -> 1 uint32,
// bit j = signbit(col j)) and pack sign(w_fc) rows (25 bits per (ci,k)).
__global__ __launch_bounds__(256) void pack_kernel(
    const float* __restrict__ x, const float* __restrict__ w_fc,
    uint32_t* __restrict__ xp, uint32_t* __restrict__ wfp)
{
  int t = blockIdx.x * 256 + threadIdx.x;
  if (t < XWORDS) {
    const float4* p = (const float4*)(x + (size_t)t * 28);  // 112B-aligned
    uint32_t m = 0;
    #pragma unroll
    for (int q = 0; q < 7; ++q) {
      float4 v = p[q];
      m = (m >> 1) | (__float_as_uint(v.x) & 0x80000000u);
      m = (m >> 1) | (__float_as_uint(v.y) & 0x80000000u);
      m = (m >> 1) | (__float_as_uint(v.z) & 0x80000000u);
      m = (m >> 1) | (__float_as_uint(v.w) & 0x80000000u);
    }
    xp[t] = m >> 4;   // sign(col j) lands at bit j
  } else {
    int s = t - XWORDS;
    if (s < 750) {                    // 75 (c,i) rows x 10 outputs
      int ci = s / 10, k = s % 10;
      uint32_t m = 0;
      #pragma unroll
      for (int j = 0; j < 25; ++j)
        m |= (__float_as_uint(w_fc[k * 1875 + ci * 25 + j]) >> 31) << j;
      wfp[ci * 12 + k] = m;           // [75][12] padded for 16B-aligned reads
    }
  }
}

// Pass 2: 1 thread = 1 image. CSA bit-plane conv (all 25 cols of a (c,i) row at
// once) + popcount FC, all in registers/LDS.
__global__ __launch_bounds__(256) void bnn_main(
    const uint32_t* __restrict__ xp, const uint32_t* __restrict__ wfp,
    const float* __restrict__ w_conv, const float* __restrict__ b_conv,
    const float* __restrict__ b_fc, float* __restrict__ out)
{
  __shared__ __align__(16) uint32_t swf[900];      // packed w_fc rows
  __shared__ uint32_t srows[256 * 29];             // stride 29: odd -> no bank conflicts
  const int tid = threadIdx.x;
  const int b = blockIdx.x * 256 + tid;

  for (int i = tid; i < 900; i += 256) swf[i] = wfp[i];

  // load my 28 packed rows into my private LDS slice
  const uint4* rp = (const uint4*)(xp + (size_t)b * 28);  // 112B-aligned
  uint32_t* my = &srows[tid * 29];
  #pragma unroll
  for (int q = 0; q < 7; ++q) {
    uint4 v = rp[q];
    my[q * 4 + 0] = v.x; my[q * 4 + 1] = v.y;
    my[q * 4 + 2] = v.z; my[q * 4 + 3] = v.w;
  }
  __syncthreads();  // for swf

  // conv weight sign masks (uniform -> SGPRs): wm = signbit(w) ? ~0 : 0
  uint32_t wm[3][16], sbc[3];
  #pragma unroll
  for (int c = 0; c < 3; ++c) {
    #pragma unroll
    for (int uv = 0; uv < 16; ++uv)
      wm[c][uv] = (uint32_t)((int32_t)__float_as_uint(w_conv[c * 16 + uv]) >> 31);
    sbc[c] = (uint32_t)((int32_t)__float_as_uint(b_conv[c]) >> 31);
  }

  int nd[10] = {0, 0, 0, 0, 0, 0, 0, 0, 0, 0};

  for (int i = 0; i < 25; ++i) {
    uint32_t r0 = my[i], r1 = my[i + 1], r2 = my[i + 2], r3 = my[i + 3];
    #pragma unroll
    for (int c = 0; c < 3; ++c) {
      const uint32_t* W = wm[c];
      // 16 disagreement bit-vectors, bit j = x[i+u][j+v] sign ^ w[c][u][v] sign
      uint32_t s0, c0, s1, c1, s2, c2, s3, c3, s4, c4;
      FA( r0 ^ W[0],        (r0 ^ W[1])  >> 1, (r0 ^ W[2])  >> 2, s0, c0);
      FA((r0 ^ W[3]) >> 3,   r1 ^ W[4],        (r1 ^ W[5])  >> 1, s1, c1);
      FA((r1 ^ W[6]) >> 2,  (r1 ^ W[7])  >> 3,  r2 ^ W[8],        s2, c2);
      FA((r2 ^ W[9]) >> 1,  (r2 ^ W[10]) >> 2, (r2 ^ W[11]) >> 3, s3, c3);
      FA( r3 ^ W[12],       (r3 ^ W[13]) >> 1, (r3 ^ W[14]) >> 2, s4, c4);
      uint32_t t15 = (r3 ^ W[15]) >> 3;
      // weight-1 plane: s0..s4, t15
      uint32_t u0, d0, u1, d1;
      FA(s0, s1, s2, u0, d0); FA(s3, s4, t15, u1, d1);
      uint32_t bb0 = u0 ^ u1, e0 = u0 & u1;
      // weight-2 plane: c0..c4, d0, d1, e0
      uint32_t p0, q0, p1, q1, p2, q2;
      FA(c0, c1, c2, p0, q0); FA(c3, c4, d0, p1, q1); FA(d1, e0, p0, p2, q2);
      uint32_t bb1 = p1 ^ p2, q3 = p1 & p2;
      // weight-4 plane: q0..q3
      uint32_t r0_, r1_;
      FA(q0, q1, q2, r0_, r1_);
      uint32_t bb2 = r0_ ^ q3, r2_ = r0_ & q3;
      uint32_t bb3 = r1_ ^ r2_, bb4 = r1_ & r2_;
      // Nd per col j = bb0+2bb1+4bb2+8bb3+16bb4; h<0 <=> Nd>8 or (Nd==8 & b_c<0)
      uint32_t low = bb0 | bb1 | bb2;
      uint32_t neg = (bb4 | (bb3 & (low | sbc[c]))) & 0x1FFFFFFu;
      // FC accumulate: Nd_fc[k] += popc(hrow ^ wfrow[k])
      int ci = c * 25 + i;
      uint4 wA = *(const uint4*)&swf[ci * 12];
      uint4 wB = *(const uint4*)&swf[ci * 12 + 4];
      uint2 wC = *(const uint2*)&swf[ci * 12 + 8];
      nd[0] += __popc(neg ^ wA.x); nd[1] += __popc(neg ^ wA.y);
      nd[2] += __popc(neg ^ wA.z); nd[3] += __popc(neg ^ wA.w);
      nd[4] += __popc(neg ^ wB.x); nd[5] += __popc(neg ^ wB.y);
      nd[6] += __popc(neg ^ wB.z); nd[7] += __popc(neg ^ wB.w);
      nd[8] += __popc(neg ^ wC.x); nd[9] += __popc(neg ^ wC.y);
    }
  }

  float* op = out + (size_t)b * 10;
  #pragma unroll
  for (int k = 0; k < 10; k += 2) {
    float v0 = (float)(1875 - 2 * nd[k])     + b_fc[k];
    float v1 = (float)(1875 - 2 * nd[k + 1]) + b_fc[k + 1];
    float2 st;
    st.x = v0 < 0.f ? -1.f : (v0 > 0.f ? 1.f : 0.f);
    st.y = v1 < 0.f ? -1.f : (v1 > 0.f ? 1.f : 0.f);
    *(float2*)(op + k) = st;  // 8B-aligned (b*40)
  }
}

extern "C" void kernel_launch(void* const* d_in, const int* in_sizes, int n_in,
                              void* d_out, int out_size, void* d_ws, size_t ws_size,
                              hipStream_t stream) {
  const float* x      = (const float*)d_in[0];
  const float* w_conv = (const float*)d_in[1];
  const float* b_conv = (const float*)d_in[2];
  const float* w_fc   = (const float*)d_in[3];
  const float* b_fc   = (const float*)d_in[4];

  uint32_t* xp  = (uint32_t*)d_ws;        // 7.0 MB packed sign rows
  uint32_t* wfp = xp + XWORDS;            // 900 words packed fc weights

  // pass 1: 7168 blocks pack x rows, 3 extra blocks pack w_fc
  pack_kernel<<<7171, 256, 0, stream>>>(x, w_fc, xp, wfp);
  // pass 2: 1 thread per image
  bnn_main<<<256, 256, 0, stream>>>(xp, wfp, w_conv, b_conv, b_fc, (float*)d_out);
}

// Round 2
// 303.696 us; speedup vs baseline: 1.0020x; 1.0020x over previous
//
#include <hip/hip_runtime.h>
#include <stdint.h>

#define IMB 64              // images per block
#define NBLK (65536 / IMB)  // 1024 blocks

__device__ __forceinline__ void FA(uint32_t a, uint32_t b, uint32_t c,
                                   uint32_t& s, uint32_t& cy) {
  uint32_t ab = a ^ b;
  s = ab ^ c;
  cy = (a & b) | (ab & c);
}

// One fused kernel. Per block: 64 images.
//  A: coalesced float4 reads of x -> sign nibbles in LDS
//  B: pack 28-bit row words
//  C: 4 threads/image, CSA bit-plane binary conv + XNOR-popcount FC, shfl reduce
__global__ __launch_bounds__(256) void bnn_fused(
    const float* __restrict__ x, const float* __restrict__ w_conv,
    const float* __restrict__ b_conv, const float* __restrict__ w_fc,
    const float* __restrict__ b_fc, float* __restrict__ out)
{
  __shared__ uint8_t  nib[IMB * 196];           // 12544 B: one nibble per float4
  __shared__ uint32_t srows[IMB * 29];          // stride 29 (odd) -> conflict-free
  __shared__ __align__(16) uint32_t swf[900];   // packed w_fc [75 ci][12 pad]
  const int tid = threadIdx.x;

  // conv weight sign masks (uniform addresses -> scalar loads / SGPRs)
  uint32_t wm[3][16], sbc[3];
#pragma unroll
  for (int c = 0; c < 3; ++c) {
#pragma unroll
    for (int uv = 0; uv < 16; ++uv)
      wm[c][uv] = (uint32_t)((int32_t)__float_as_uint(w_conv[c * 16 + uv]) >> 31);
    sbc[c] = (uint32_t)((int32_t)__float_as_uint(b_conv[c]) >> 31);
  }

  // unpack w_fc sign bits (redundant per block; 75 KB stays L2-resident)
  for (int s = tid; s < 750; s += 256) {
    int ci = s / 10, k = s - ci * 10;
    const float* wr = w_fc + k * 1875 + ci * 25;
    uint32_t m = 0;
#pragma unroll
    for (int j = 0; j < 25; ++j)
      m |= (__float_as_uint(wr[j]) >> 31) << j;
    swf[ci * 12 + k] = m;
  }

  // --- phase A: fully coalesced loads (16B/lane, consecutive across lanes) ---
  const float4* xv = (const float4*)(x + (size_t)blockIdx.x * (IMB * 784));
#pragma unroll 4
  for (int q = 0; q < 49; ++q) {
    int idx = q * 256 + tid;
    float4 v = xv[idx];
    uint32_t n = (__float_as_uint(v.x) >> 31)
               | ((__float_as_uint(v.y) >> 31) << 1)
               | ((__float_as_uint(v.z) >> 31) << 2)
               | ((__float_as_uint(v.w) >> 31) << 3);
    nib[idx] = (uint8_t)n;   // nibble g covers cols 4j..4j+3 of row g/7
  }
  __syncthreads();

  // --- phase B: assemble 28-bit row words from 7 nibbles ---
#pragma unroll
  for (int q = 0; q < 7; ++q) {
    int r = q * 256 + tid;   // 0..1791 (= 64 images * 28 rows)
    const uint8_t* p = &nib[r * 7];
    uint32_t m = (uint32_t)p[0]        | ((uint32_t)p[1] << 4)
               | ((uint32_t)p[2] << 8) | ((uint32_t)p[3] << 12)
               | ((uint32_t)p[4] << 16)| ((uint32_t)p[5] << 20)
               | ((uint32_t)p[6] << 24);
    int mi = r / 28, rowin = r - mi * 28;
    srows[mi * 29 + rowin] = m;
  }
  __syncthreads();

  // --- phase C: 4 threads per image, i-ranges {0-6,7-13,14-20,21-24} ---
  const int sub = tid & 3;
  const int img = tid >> 2;               // 0..63
  const uint32_t* my = &srows[img * 29];
  int nd[10] = {0,0,0,0,0,0,0,0,0,0};
  int ilo = sub * 7;
  int ihi = ilo + 7; if (ihi > 25) ihi = 25;

  for (int i = ilo; i < ihi; ++i) {
    uint32_t r0 = my[i], r1 = my[i + 1], r2 = my[i + 2], r3 = my[i + 3];
#pragma unroll
    for (int c = 0; c < 3; ++c) {
      const uint32_t* W = wm[c];
      uint32_t s0, c0, s1, c1, s2, c2, s3, c3, s4, c4;
      FA( r0 ^ W[0],        (r0 ^ W[1])  >> 1, (r0 ^ W[2])  >> 2, s0, c0);
      FA((r0 ^ W[3]) >> 3,   r1 ^ W[4],        (r1 ^ W[5])  >> 1, s1, c1);
      FA((r1 ^ W[6]) >> 2,  (r1 ^ W[7])  >> 3,  r2 ^ W[8],        s2, c2);
      FA((r2 ^ W[9]) >> 1,  (r2 ^ W[10]) >> 2, (r2 ^ W[11]) >> 3, s3, c3);
      FA( r3 ^ W[12],       (r3 ^ W[13]) >> 1, (r3 ^ W[14]) >> 2, s4, c4);
      uint32_t t15 = (r3 ^ W[15]) >> 3;
      // weight-1 plane
      uint32_t u0, d0, u1, d1;
      FA(s0, s1, s2, u0, d0); FA(s3, s4, t15, u1, d1);
      uint32_t bb0 = u0 ^ u1, e0 = u0 & u1;
      // weight-2 plane
      uint32_t p0, q0, p1, q1, p2, q2;
      FA(c0, c1, c2, p0, q0); FA(c3, c4, d0, p1, q1); FA(d1, e0, p0, p2, q2);
      uint32_t bb1 = p1 ^ p2, q3 = p1 & p2;
      // weight-4 plane
      uint32_t r0_, r1_;
      FA(q0, q1, q2, r0_, r1_);
      uint32_t bb2 = r0_ ^ q3, r2_ = r0_ & q3;
      uint32_t bb3 = r1_ ^ r2_, bb4 = r1_ & r2_;
      // Nd>8, or Nd==8 with negative conv bias -> h sign bit
      uint32_t low = bb0 | bb1 | bb2;
      uint32_t neg = (bb4 | (bb3 & (low | sbc[c]))) & 0x1FFFFFFu;
      int ci = c * 25 + i;
      uint4 wA = *(const uint4*)&swf[ci * 12];
      uint4 wB = *(const uint4*)&swf[ci * 12 + 4];
      uint2 wC = *(const uint2*)&swf[ci * 12 + 8];
      nd[0] += __popc(neg ^ wA.x); nd[1] += __popc(neg ^ wA.y);
      nd[2] += __popc(neg ^ wA.z); nd[3] += __popc(neg ^ wA.w);
      nd[4] += __popc(neg ^ wB.x); nd[5] += __popc(neg ^ wB.y);
      nd[6] += __popc(neg ^ wB.z); nd[7] += __popc(neg ^ wB.w);
      nd[8] += __popc(neg ^ wC.x); nd[9] += __popc(neg ^ wC.y);
    }
  }

  // reduce partial mismatch counts across the 4 subs (lanes 4m..4m+3)
#pragma unroll
  for (int k = 0; k < 10; ++k) nd[k] += __shfl_xor(nd[k], 1);
#pragma unroll
  for (int k = 0; k < 10; ++k) nd[k] += __shfl_xor(nd[k], 2);

  if (sub == 0) {
    const size_t bi = (size_t)blockIdx.x * IMB + img;
    float* op = out + bi * 10;
#pragma unroll
    for (int k = 0; k < 10; k += 2) {
      float v0 = (float)(1875 - 2 * nd[k])     + b_fc[k];
      float v1 = (float)(1875 - 2 * nd[k + 1]) + b_fc[k + 1];
      float2 st;
      st.x = v0 < 0.f ? -1.f : (v0 > 0.f ? 1.f : 0.f);
      st.y = v1 < 0.f ? -1.f : (v1 > 0.f ? 1.f : 0.f);
      *(float2*)(op + k) = st;   // 8B aligned (bi*40)
    }
  }
}

extern "C" void kernel_launch(void* const* d_in, const int* in_sizes, int n_in,
                              void* d_out, int out_size, void* d_ws, size_t ws_size,
                              hipStream_t stream) {
  const float* x      = (const float*)d_in[0];
  const float* w_conv = (const float*)d_in[1];
  const float* b_conv = (const float*)d_in[2];
  const float* w_fc   = (const float*)d_in[3];
  const float* b_fc   = (const float*)d_in[4];
  bnn_fused<<<NBLK, 256, 0, stream>>>(x, w_conv, b_conv, w_fc, b_fc,
                                      (float*)d_out);
}